// Round 5
// baseline (635.456 us; speedup 1.0000x reference)
//
#include <hip/hip_runtime.h>
#include <math.h>

// Problem constants
#define BATCH  4
#define LSEQ   2048
#define DMODEL 1024
#define MROWS  (BATCH * LSEQ)   // 8192
#define SCORE_SCALE 8.0f        // sqrt(1024/16), reference MULTIPLIES

#define THREEFRY_PARTITIONABLE 1  // verified correct in round 1

typedef __bf16 bf16_t;
typedef bf16_t bf16x8 __attribute__((ext_vector_type(8)));
typedef bf16_t bf16x4 __attribute__((ext_vector_type(4)));
typedef float  f32x16 __attribute__((ext_vector_type(16)));

#define LDSP(p) ((__attribute__((address_space(3))) void*)(p))
#define GLBP(p) ((const __attribute__((address_space(1))) void*)(p))

// ---------------------------------------------------------------------------
// threefry dropout (verified round 1)
// ---------------------------------------------------------------------------
__device__ __forceinline__ unsigned rotl32(unsigned x, int r) {
    return (x << r) | (x >> (32 - r));
}

__device__ __forceinline__ void threefry2x32(unsigned k0, unsigned k1,
                                             unsigned x0, unsigned x1,
                                             unsigned& o0, unsigned& o1) {
    const unsigned ks0 = k0, ks1 = k1, ks2 = k0 ^ k1 ^ 0x1BD11BDAu;
    x0 += ks0; x1 += ks1;
#define TF_R(r) { x0 += x1; x1 = rotl32(x1, r); x1 ^= x0; }
    TF_R(13) TF_R(15) TF_R(26) TF_R(6)
    x0 += ks1; x1 += ks2 + 1u;
    TF_R(17) TF_R(29) TF_R(16) TF_R(24)
    x0 += ks2; x1 += ks0 + 2u;
    TF_R(13) TF_R(15) TF_R(26) TF_R(6)
    x0 += ks0; x1 += ks1 + 3u;
    TF_R(17) TF_R(29) TF_R(16) TF_R(24)
    x0 += ks1; x1 += ks2 + 4u;
    TF_R(13) TF_R(15) TF_R(26) TF_R(6)
    x0 += ks2; x1 += ks0 + 5u;
#undef TF_R
    o0 = x0; o1 = x1;
}

__device__ __forceinline__ bool dropout_keep(unsigned n) {
    unsigned o0, o1;
#if THREEFRY_PARTITIONABLE
    threefry2x32(0u, 42u, 0u, n, o0, o1);
    unsigned bits = o0 ^ o1;
#else
    const unsigned HALF = (unsigned)(BATCH * LSEQ) * (unsigned)LSEQ / 2u;
    unsigned c0 = (n < HALF) ? n : (n - HALF);
    unsigned c1 = (n < HALF) ? (n + HALF) : n;
    threefry2x32(0u, 42u, c0, c1, o0, o1);
    unsigned bits = (n < HALF) ? o0 : o1;
#endif
    return bits < 0x80000000u;
}

// ---------------------------------------------------------------------------
// Split fp32 -> bf16 hi/lo. grid.y selects input (X0/X1), output offset y*n.
// ---------------------------------------------------------------------------
__global__ __launch_bounds__(256)
void split_f32(const float* __restrict__ X0, const float* __restrict__ X1,
               bf16_t* __restrict__ hi, bf16_t* __restrict__ lo, int n) {
    const int y = blockIdx.y;
    const float* X = y ? X1 : X0;
    long long i = (long long)(blockIdx.x * 256 + threadIdx.x) * 4;
    if (i >= n) return;
    float4 v = *(const float4*)(X + i);
    bf16x4 h, l;
    h[0] = (bf16_t)v.x; l[0] = (bf16_t)(v.x - (float)h[0]);
    h[1] = (bf16_t)v.y; l[1] = (bf16_t)(v.y - (float)h[1]);
    h[2] = (bf16_t)v.z; l[2] = (bf16_t)(v.z - (float)h[2]);
    h[3] = (bf16_t)v.w; l[3] = (bf16_t)(v.w - (float)h[3]);
    *(bf16x4*)(hi + (long long)y * n + i) = h;
    *(bf16x4*)(lo + (long long)y * n + i) = l;
}

// plain fp32 -> bf16 convert (V path needs only hi plane)
__global__ __launch_bounds__(256)
void cvt_bf16(const float* __restrict__ X, bf16_t* __restrict__ Y, int n) {
    long long i = (long long)(blockIdx.x * 256 + threadIdx.x) * 8;
    if (i >= n) return;
    float4 a = *(const float4*)(X + i);
    float4 b = *(const float4*)(X + i + 4);
    bf16x8 o;
    o[0] = (bf16_t)a.x; o[1] = (bf16_t)a.y; o[2] = (bf16_t)a.z; o[3] = (bf16_t)a.w;
    o[4] = (bf16_t)b.x; o[5] = (bf16_t)b.y; o[6] = (bf16_t)b.z; o[7] = (bf16_t)b.w;
    *(bf16x8*)(Y + i) = o;
}

// W fp32 [K][N] -> W^T hi/lo bf16 [N][K]; grid.z selects W0/W1, out += z*K*N
__global__ __launch_bounds__(256)
void split_transpose(const float* __restrict__ W0, const float* __restrict__ W1,
                     bf16_t* __restrict__ Th, bf16_t* __restrict__ Tl,
                     int Kd, int Nd) {
    __shared__ float t[32][33];
    const int z = blockIdx.z;
    const float* W = z ? W1 : W0;
    const long long zo = (long long)z * Kd * Nd;
    const int bx = blockIdx.x * 32;  // n
    const int by = blockIdx.y * 32;  // k
    const int tx = threadIdx.x & 31, ty = threadIdx.x >> 5;  // 32x8
#pragma unroll
    for (int i = 0; i < 4; ++i)
        t[ty + i * 8][tx] = W[(long long)(by + ty + i * 8) * Nd + bx + tx];
    __syncthreads();
#pragma unroll
    for (int i = 0; i < 4; ++i) {
        float v = t[tx][ty + i * 8];
        long long idx = zo + (long long)(bx + ty + i * 8) * Kd + by + tx;
        bf16_t h = (bf16_t)v;
        Th[idx] = h;
        Tl[idx] = (bf16_t)(v - (float)h);
    }
}

// ---------------------------------------------------------------------------
// MFMA GEMM: C[M,N] = scale * (Ah+Al)[M,K] @ (Bh+Bl)[N,K]^T (+bias)
// 128x128 tile, BK=32, 4 waves (2x2), wave = 2x2 subtiles of 32x32 MFMA
// (v_mfma_f32_32x32x16_bf16: +20% pipe rate vs 16x16x32, m119).
// A: LDS double-buffered via global_load_lds + manual vmcnt + raw s_barrier
//    (XOR-swizzled layout, conflicts == 0 verified r3/r4).
// B: DIRECT-TO-VGPR — K-major layout makes each lane's 16B fragment
//    contiguous; loaded with plain global dwordx4, no LDS at all.
// SPLIT: 3 MFMAs per product (hi*hi + hi*lo + lo*hi).
// OUT: 0 = fp32*scale, 1 = bf16 hi/lo pair (+bias), 2 = bf16 (+bias)
// BROW: bias indexed by row m. bias2: z==1 bias (fused Q/K projections).
// ---------------------------------------------------------------------------
template <int SPLIT, int OUT, int BROW>
__global__ __launch_bounds__(256, 3)
void gemm_mfma(const bf16_t* __restrict__ Ah, const bf16_t* __restrict__ Al,
               const bf16_t* __restrict__ Bh, const bf16_t* __restrict__ Bl,
               const float* __restrict__ bias, const float* __restrict__ bias2,
               float* __restrict__ Cf, bf16_t* __restrict__ Ch,
               bf16_t* __restrict__ Cl,
               int M, int N, int K, float scale,
               long long sA, long long sB, long long sC) {
    constexpr int PL = 128 * 32;            // elements per A plane
    constexpr int NP = SPLIT ? 2 : 1;
    constexpr int BUFSZ = NP * PL;
    __shared__ __align__(16) bf16_t smem[2 * BUFSZ];  // split 32KB, plain 16KB

    const int tid = threadIdx.x;
    const int lane = tid & 63;
    const int wave = tid >> 6;
    const int l32 = lane & 31;
    const int ksel = lane >> 5;             // k-half within 8-elem fragment
    const int wm = (wave & 1) * 64;
    const int wn = (wave >> 1) * 64;
    const long long z = blockIdx.z;
    const int m0 = blockIdx.y * 128, n0 = blockIdx.x * 128;

    const bf16_t* gAh = Ah + z * sA;
    const bf16_t* gAl = SPLIT ? Al + z * sA : nullptr;
    const bf16_t* gBh = Bh + z * sB;
    const bf16_t* gBl = SPLIT ? Bl + z * sB : nullptr;

    // A staging lane geometry: per chunk 16 rows x 4 col-groups of 16B,
    // global col-group XOR-swizzled; HW writes LDS linearly (lane*16B).
    const int lrow = lane >> 2;                               // 0..15
    const int sgrp = ((lane & 3) ^ ((lrow >> 1) & 3)) * 8;    // elements

    // B per-lane fragment row pointers (16B contiguous in K-major)
    const bf16_t* pBh[2];
    const bf16_t* pBl[2];
#pragma unroll
    for (int j = 0; j < 2; ++j) {
        const long long nn = (long long)(n0 + wn + j * 32 + l32) * K + ksel * 8;
        pBh[j] = gBh + nn;
        if constexpr (SPLIT) pBl[j] = gBl + nn;
    }

    auto issueA = [&](int k0, int b) {
        bf16_t* base = smem + b * BUFSZ;
#pragma unroll
        for (int c = 0; c < 2; ++c) {
            const int row = wave * 32 + c * 16 + lrow;
            const long long g = (long long)(m0 + row) * K + k0 + sgrp;
            __builtin_amdgcn_global_load_lds(GLBP(gAh + g), LDSP(base + row * 32), 16, 0, 0);
            if constexpr (SPLIT)
                __builtin_amdgcn_global_load_lds(GLBP(gAl + g), LDSP(base + PL + row * 32), 16, 0, 0);
        }
    };

    f32x16 acc[2][2];
#pragma unroll
    for (int i = 0; i < 2; ++i)
#pragma unroll
        for (int j = 0; j < 2; ++j)
#pragma unroll
            for (int r = 0; r < 16; ++r) acc[i][j][r] = 0.f;

    bf16x8 bh[2][2], bl[2][2];   // [j][kh]

    issueA(0, 0);
    const int NIT = K >> 5;
    for (int it = 0; it < NIT; ++it) {
        const int b = it & 1;
        const bool more = (it + 1) < NIT;
        const int k0 = it << 5;
        // B fragments for THIS iter (oldest vmem -> compiler waits don't
        // stall on the A prefetch behind them)
#pragma unroll
        for (int j = 0; j < 2; ++j)
#pragma unroll
            for (int kh = 0; kh < 2; ++kh) {
                bh[j][kh] = *(const bf16x8*)(pBh[j] + k0 + kh * 16);
                if constexpr (SPLIT) bl[j][kh] = *(const bf16x8*)(pBl[j] + k0 + kh * 16);
            }
        if (more) issueA(k0 + 32, b ^ 1);
        // guarantee this iter's A (issued last iter, older than everything
        // above) has landed in LDS; leave the fresh loads in flight
        if constexpr (SPLIT) {
            if (more) asm volatile("s_waitcnt vmcnt(12)" ::: "memory");
            else      asm volatile("s_waitcnt vmcnt(8)" ::: "memory");
        } else {
            if (more) asm volatile("s_waitcnt vmcnt(6)" ::: "memory");
            else      asm volatile("s_waitcnt vmcnt(4)" ::: "memory");
        }
        asm volatile("s_barrier" ::: "memory");

        bf16_t* base = smem + b * BUFSZ;
        const int sw = (l32 >> 1) & 3;
        bf16x8 ah[2][2], al[2][2];
#pragma unroll
        for (int i = 0; i < 2; ++i)
#pragma unroll
            for (int kh = 0; kh < 2; ++kh) {
                const int r = wm + i * 32 + l32;
                const int g = ((kh * 2 + ksel) ^ sw) * 8;
                ah[i][kh] = *(const bf16x8*)(base + r * 32 + g);
                if constexpr (SPLIT) al[i][kh] = *(const bf16x8*)(base + PL + r * 32 + g);
            }
#pragma unroll
        for (int kh = 0; kh < 2; ++kh)
#pragma unroll
            for (int i = 0; i < 2; ++i)
#pragma unroll
                for (int j = 0; j < 2; ++j) {
                    acc[i][j] = __builtin_amdgcn_mfma_f32_32x32x16_bf16(ah[i][kh], bh[j][kh], acc[i][j], 0, 0, 0);
                    if constexpr (SPLIT) {
                        acc[i][j] = __builtin_amdgcn_mfma_f32_32x32x16_bf16(ah[i][kh], bl[j][kh], acc[i][j], 0, 0, 0);
                        acc[i][j] = __builtin_amdgcn_mfma_f32_32x32x16_bf16(al[i][kh], bh[j][kh], acc[i][j], 0, 0, 0);
                    }
                }
        asm volatile("s_barrier" ::: "memory");  // all waves done with buf[b]
    }

    const float* bz = (z == 1 && bias2) ? bias2 : bias;
    // 32x32 C/D layout: col = lane&31, row = (reg&3) + 8*(reg>>2) + 4*(lane>>5)
#pragma unroll
    for (int i = 0; i < 2; ++i)
#pragma unroll
        for (int j = 0; j < 2; ++j) {
            const int n = n0 + wn + j * 32 + l32;
            float bvn = 0.f;
            if constexpr (OUT != 0 && !BROW) bvn = bz[n];
#pragma unroll
            for (int reg = 0; reg < 16; ++reg) {
                const int rr = (reg & 3) + 8 * (reg >> 2) + 4 * ksel;
                const int m = m0 + wm + i * 32 + rr;
                const long long idx = z * sC + (long long)m * N + n;
                float v = acc[i][j][reg];
                if constexpr (OUT == 0) {
                    Cf[idx] = v * scale;
                } else if constexpr (OUT == 1) {
                    v += bvn;
                    bf16_t h = (bf16_t)v;
                    Ch[idx] = h;
                    Cl[idx] = (bf16_t)(v - (float)h);
                } else {
                    v += BROW ? bz[m] : bvn;
                    Ch[idx] = (bf16_t)v;
                }
            }
        }
}

// ---------------------------------------------------------------------------
// Row softmax + dropout, register-resident: 256 thr x 8 elems, shuffle
// reductions, tiny LDS -> high occupancy. S fp32 -> P bf16.
// ---------------------------------------------------------------------------
__global__ __launch_bounds__(256)
void softmax_dropout(const float* __restrict__ S, bf16_t* __restrict__ P) {
    const unsigned row = blockIdx.x;
    const float* rp = S + (long long)row * LSEQ;
    const int tid = threadIdx.x;

    float v[8];
    *(float4*)(v)     = *(const float4*)(rp + tid * 8);
    *(float4*)(v + 4) = *(const float4*)(rp + tid * 8 + 4);

    float m = v[0];
#pragma unroll
    for (int e = 1; e < 8; ++e) m = fmaxf(m, v[e]);
#pragma unroll
    for (int o = 1; o < 64; o <<= 1) m = fmaxf(m, __shfl_xor(m, o));
    __shared__ float redm[4];
    if ((tid & 63) == 0) redm[tid >> 6] = m;
    __syncthreads();
    m = fmaxf(fmaxf(redm[0], redm[1]), fmaxf(redm[2], redm[3]));

    float s = 0.f;
#pragma unroll
    for (int e = 0; e < 8; ++e) { v[e] = __expf(v[e] - m); s += v[e]; }
#pragma unroll
    for (int o = 1; o < 64; o <<= 1) s += __shfl_xor(s, o);
    __shared__ float reds[4];
    if ((tid & 63) == 0) reds[tid >> 6] = s;
    __syncthreads();
    s = (reds[0] + reds[1]) + (reds[2] + reds[3]);

    const float inv = 2.0f / s;  // dropout /0.5 folded in
    const unsigned nb = row * (unsigned)LSEQ + (unsigned)(tid * 8);
    bf16x8 o8;
#pragma unroll
    for (int e = 0; e < 8; ++e)
        o8[e] = (bf16_t)(dropout_keep(nb + e) ? v[e] * inv : 0.0f);
    *(bf16x8*)(P + (long long)row * LSEQ + tid * 8) = o8;
}

// ---------------------------------------------------------------------------
extern "C" void kernel_launch(void* const* d_in, const int* in_sizes, int n_in,
                              void* d_out, int out_size, void* d_ws, size_t ws_size,
                              hipStream_t stream) {
    const float* query = (const float*)d_in[0];
    const float* key_  = (const float*)d_in[1];
    const float* value = (const float*)d_in[2];
    const float* Wq = (const float*)d_in[3];
    const float* bq = (const float*)d_in[4];
    const float* Wk = (const float*)d_in[5];
    const float* bk = (const float*)d_in[6];
    const float* Wv = (const float*)d_in[7];
    const float* bv = (const float*)d_in[8];
    float* out = (float*)d_out;

    // ws layout (bytes), Q1 = 8192*1024*2 = 16.78MB; total 9*Q1 + 8.4MB = 159.4MB
    char* w = (char*)d_ws;
    const size_t Q1 = (size_t)MROWS * DMODEL * 2;
    bf16_t* Qh  = (bf16_t*)(w);               // [0,2Q1): Qh,Kh  (z-stride NELEM)
    bf16_t* Ql  = (bf16_t*)(w + 2 * Q1);      // [2Q1,4Q1): Ql,Kl
    bf16_t* VT  = (bf16_t*)(w + 4 * Q1);      // [4Q1,5Q1): V^T per batch [D][LK]
    float*  S   = (float*)(w + 5 * Q1);       // [5Q1,9Q1) fp32 scores
    // phase-A aliases inside S region:
    bf16_t* XvH  = (bf16_t*)(w + 5 * Q1);     // V bf16 (hi only)
    bf16_t* XqkH = (bf16_t*)(w + 5 * Q1);     // QK split hi (z-stride NELEM)
    bf16_t* XqkL = (bf16_t*)(w + 7 * Q1);     // QK split lo (z-stride NELEM)
    bf16_t* WTh = (bf16_t*)(w + 9 * Q1);      // 2 z-slots of D*D
    bf16_t* WTl = (bf16_t*)(w + 9 * Q1 + 2 * (size_t)DMODEL * DMODEL * 2);
    bf16_t* P   = Qh;  // [0,2Q1) aliases Qh+Kh (dead after QK^T)

    dim3 b256(256);
    const int NELEM = MROWS * DMODEL;
    const long long DD = (long long)DMODEL * DMODEL;
    dim3 gwt1(DMODEL / 32, DMODEL / 32, 1);
    dim3 gwt2(DMODEL / 32, DMODEL / 32, 2);

    // --- V path: V^T = Wv^T @ X^T directly (plain bf16, row-bias)
    split_transpose<<<gwt1, b256, 0, stream>>>(Wv, nullptr, WTh, WTl, DMODEL, DMODEL);
    cvt_bf16<<<dim3(NELEM / 2048), b256, 0, stream>>>(value, XvH, NELEM);
    gemm_mfma<0, 2, 1><<<dim3(LSEQ / 128, DMODEL / 128, BATCH), b256, 0, stream>>>(
        WTh, nullptr, XvH, nullptr, bv, nullptr, nullptr, VT, nullptr,
        DMODEL, LSEQ, DMODEL, 1.f,
        0, (long long)LSEQ * DMODEL, (long long)DMODEL * LSEQ);

    // --- Q and K projections, fused over grid.z (split precision)
    split_transpose<<<gwt2, b256, 0, stream>>>(Wq, Wk, WTh, WTl, DMODEL, DMODEL);
    split_f32<<<dim3(NELEM / 1024, 2), b256, 0, stream>>>(query, key_, XqkH, XqkL, NELEM);
    gemm_mfma<1, 1, 0><<<dim3(DMODEL / 128, MROWS / 128, 2), b256, 0, stream>>>(
        XqkH, XqkL, WTh, WTl, bq, bk, nullptr, Qh, Ql,
        MROWS, DMODEL, DMODEL, 1.f,
        (long long)NELEM, DD, (long long)NELEM);

    // --- S = 8 * Q K^T (batched, split precision)
    gemm_mfma<1, 0, 0><<<dim3(LSEQ / 128, LSEQ / 128, BATCH), b256, 0, stream>>>(
        Qh, Ql, Qh + NELEM, Ql + NELEM, nullptr, nullptr, S, nullptr, nullptr,
        LSEQ, LSEQ, DMODEL, SCORE_SCALE,
        (long long)LSEQ * DMODEL, (long long)LSEQ * DMODEL,
        (long long)LSEQ * LSEQ);

    // --- softmax + dropout -> P bf16 (aliases Qh/Kh region)
    softmax_dropout<<<dim3(MROWS), b256, 0, stream>>>(S, P);

    // --- O = P V (plain bf16), B operand = V^T [D][LK] per batch
    gemm_mfma<0, 0, 0><<<dim3(DMODEL / 128, LSEQ / 128, BATCH), b256, 0, stream>>>(
        P, nullptr, VT, nullptr, nullptr, nullptr, out, nullptr, nullptr,
        LSEQ, DMODEL, LSEQ, 1.f,
        (long long)LSEQ * LSEQ, (long long)DMODEL * LSEQ,
        (long long)LSEQ * DMODEL);
}

// Round 6
// 477.082 us; speedup vs baseline: 1.3320x; 1.3320x over previous
//
#include <hip/hip_runtime.h>
#include <math.h>

// Problem constants
#define BATCH  4
#define LSEQ   2048
#define DMODEL 1024
#define MROWS  (BATCH * LSEQ)   // 8192
#define SCORE_SCALE 8.0f        // sqrt(1024/16), reference MULTIPLIES

#define THREEFRY_PARTITIONABLE 1  // verified correct in round 1

typedef __bf16 bf16_t;
typedef bf16_t bf16x8 __attribute__((ext_vector_type(8)));
typedef bf16_t bf16x4 __attribute__((ext_vector_type(4)));
typedef float  f32x4  __attribute__((ext_vector_type(4)));

#define LDSP(p) ((__attribute__((address_space(3))) void*)(p))
#define GLBP(p) ((const __attribute__((address_space(1))) void*)(p))

// ---------------------------------------------------------------------------
// threefry dropout (verified round 1)
// ---------------------------------------------------------------------------
__device__ __forceinline__ unsigned rotl32(unsigned x, int r) {
    return (x << r) | (x >> (32 - r));
}

__device__ __forceinline__ void threefry2x32(unsigned k0, unsigned k1,
                                             unsigned x0, unsigned x1,
                                             unsigned& o0, unsigned& o1) {
    const unsigned ks0 = k0, ks1 = k1, ks2 = k0 ^ k1 ^ 0x1BD11BDAu;
    x0 += ks0; x1 += ks1;
#define TF_R(r) { x0 += x1; x1 = rotl32(x1, r); x1 ^= x0; }
    TF_R(13) TF_R(15) TF_R(26) TF_R(6)
    x0 += ks1; x1 += ks2 + 1u;
    TF_R(17) TF_R(29) TF_R(16) TF_R(24)
    x0 += ks2; x1 += ks0 + 2u;
    TF_R(13) TF_R(15) TF_R(26) TF_R(6)
    x0 += ks0; x1 += ks1 + 3u;
    TF_R(17) TF_R(29) TF_R(16) TF_R(24)
    x0 += ks1; x1 += ks2 + 4u;
    TF_R(13) TF_R(15) TF_R(26) TF_R(6)
    x0 += ks2; x1 += ks0 + 5u;
#undef TF_R
    o0 = x0; o1 = x1;
}

__device__ __forceinline__ bool dropout_keep(unsigned n) {
    unsigned o0, o1;
#if THREEFRY_PARTITIONABLE
    threefry2x32(0u, 42u, 0u, n, o0, o1);
    unsigned bits = o0 ^ o1;
#else
    const unsigned HALF = (unsigned)(BATCH * LSEQ) * (unsigned)LSEQ / 2u;
    unsigned c0 = (n < HALF) ? n : (n - HALF);
    unsigned c1 = (n < HALF) ? (n + HALF) : n;
    threefry2x32(0u, 42u, c0, c1, o0, o1);
    unsigned bits = (n < HALF) ? o0 : o1;
#endif
    return bits < 0x80000000u;
}

// ---------------------------------------------------------------------------
// Split fp32 -> bf16 hi/lo. grid.y selects input (X0/X1), output offset y*n.
// ---------------------------------------------------------------------------
__global__ __launch_bounds__(256)
void split_f32(const float* __restrict__ X0, const float* __restrict__ X1,
               bf16_t* __restrict__ hi, bf16_t* __restrict__ lo, int n) {
    const int y = blockIdx.y;
    const float* X = y ? X1 : X0;
    long long i = (long long)(blockIdx.x * 256 + threadIdx.x) * 4;
    if (i >= n) return;
    float4 v = *(const float4*)(X + i);
    bf16x4 h, l;
    h[0] = (bf16_t)v.x; l[0] = (bf16_t)(v.x - (float)h[0]);
    h[1] = (bf16_t)v.y; l[1] = (bf16_t)(v.y - (float)h[1]);
    h[2] = (bf16_t)v.z; l[2] = (bf16_t)(v.z - (float)h[2]);
    h[3] = (bf16_t)v.w; l[3] = (bf16_t)(v.w - (float)h[3]);
    *(bf16x4*)(hi + (long long)y * n + i) = h;
    *(bf16x4*)(lo + (long long)y * n + i) = l;
}

// plain fp32 -> bf16 convert (V path needs only hi plane)
__global__ __launch_bounds__(256)
void cvt_bf16(const float* __restrict__ X, bf16_t* __restrict__ Y, int n) {
    long long i = (long long)(blockIdx.x * 256 + threadIdx.x) * 8;
    if (i >= n) return;
    float4 a = *(const float4*)(X + i);
    float4 b = *(const float4*)(X + i + 4);
    bf16x8 o;
    o[0] = (bf16_t)a.x; o[1] = (bf16_t)a.y; o[2] = (bf16_t)a.z; o[3] = (bf16_t)a.w;
    o[4] = (bf16_t)b.x; o[5] = (bf16_t)b.y; o[6] = (bf16_t)b.z; o[7] = (bf16_t)b.w;
    *(bf16x8*)(Y + i) = o;
}

// W fp32 [K][N] -> W^T hi/lo bf16 [N][K]; grid.z selects W0/W1, out += z*K*N
__global__ __launch_bounds__(256)
void split_transpose(const float* __restrict__ W0, const float* __restrict__ W1,
                     bf16_t* __restrict__ Th, bf16_t* __restrict__ Tl,
                     int Kd, int Nd) {
    __shared__ float t[32][33];
    const int z = blockIdx.z;
    const float* W = z ? W1 : W0;
    const long long zo = (long long)z * Kd * Nd;
    const int bx = blockIdx.x * 32;  // n
    const int by = blockIdx.y * 32;  // k
    const int tx = threadIdx.x & 31, ty = threadIdx.x >> 5;  // 32x8
#pragma unroll
    for (int i = 0; i < 4; ++i)
        t[ty + i * 8][tx] = W[(long long)(by + ty + i * 8) * Nd + bx + tx];
    __syncthreads();
#pragma unroll
    for (int i = 0; i < 4; ++i) {
        float v = t[tx][ty + i * 8];
        long long idx = zo + (long long)(bx + ty + i * 8) * Kd + by + tx;
        bf16_t h = (bf16_t)v;
        Th[idx] = h;
        Tl[idx] = (bf16_t)(v - (float)h);
    }
}

// ---------------------------------------------------------------------------
// MFMA GEMM (r4 core + XCD-aware tile swizzle): C = scale*(Ah+Al)(Bh+Bl)^T
// 128x128 tile, BK=32, 4 waves (2x2), 4x4 subtiles of 16x16x32 MFMA.
// Double-buffered LDS, raw s_barrier + manual vmcnt (r4: 502us, verified).
// XOR-swizzled LDS layout (0 bank conflicts, verified r3/r4).
// 1D grid, tile mapping: xcd = bid&7 owns n-stripes {xcd, xcd+8*(SX-1)...} so
// each XCD's B working set (<=1MB) stays resident in its 4MB L2 -> kills the
// 6x B re-fetch seen in r4 (FETCH 269MB vs ~42MB ideal). z slowest.
// SPLIT: 3 MFMAs/product. OUT: 0=fp32*scale, 1=bf16 hi/lo+bias, 2=bf16+bias.
// BROW: bias indexed by row m. bias2: z==1 bias (fused Q/K projections).
// ---------------------------------------------------------------------------
template <int SPLIT, int OUT, int BROW>
__global__ __launch_bounds__(256)
void gemm_mfma(const bf16_t* __restrict__ Ah, const bf16_t* __restrict__ Al,
               const bf16_t* __restrict__ Bh, const bf16_t* __restrict__ Bl,
               const float* __restrict__ bias, const float* __restrict__ bias2,
               float* __restrict__ Cf, bf16_t* __restrict__ Ch,
               bf16_t* __restrict__ Cl,
               int M, int N, int K, float scale,
               long long sA, long long sB, long long sC,
               int SX, int NYt) {
    constexpr int TM = 128, TN = 128, TOT = 256, CHUNKS = 4;
    constexpr int NB = SPLIT ? 2 : 1;
    constexpr int BUFSZ = NB * TOT * 32;
    __shared__ __align__(16) bf16_t smem[2 * BUFSZ];  // split: 64KB, plain: 32KB

    // --- XCD-aware tile mapping (1D grid) ---
    const int bid = blockIdx.x;
    const int xcd = bid & 7;
    const int ii = bid >> 3;
    const int perz = SX * NYt;
    const int zz = ii / perz;
    const int rr = ii - zz * perz;
    const int nx = xcd + ((rr % SX) << 3);
    const int my = rr / SX;
    const long long z = zz;
    const int m0 = my * TM, n0 = nx * TN;

    const int tid = threadIdx.x;
    const int lane = tid & 63;
    const int wave = tid >> 6;
    const int quad = lane >> 4;
    const int l16 = lane & 15;
    const int wm = (wave & 1) * 64;
    const int wn = (wave >> 1) * 64;

    const bf16_t* gAh = Ah + z * sA;
    const bf16_t* gBh = Bh + z * sB;
    const bf16_t* gAl = SPLIT ? Al + z * sA : nullptr;
    const bf16_t* gBl = SPLIT ? Bl + z * sB : nullptr;

    // staging lane geometry: 16 rows x 4 column-groups of 16B per chunk
    const int lrow = lane >> 2;                               // 0..15
    const int scol = ((lane & 3) ^ ((lrow >> 1) & 3)) * 8;    // swizzled col
    const int sw = (l16 >> 1) & 3;                            // read swizzle

    auto issue = [&](int k0, int b) {
        bf16_t* base = smem + b * BUFSZ;
#pragma unroll
        for (int c = 0; c < CHUNKS; ++c) {
            const int rbase = wave * 64 + c * 16;
            const int row = rbase + lrow;
            if (rbase < TM) {
                const long long g = (long long)(m0 + row) * K + k0 + scol;
                __builtin_amdgcn_global_load_lds(GLBP(gAh + g), LDSP(base + row * 32), 16, 0, 0);
                if constexpr (SPLIT)
                    __builtin_amdgcn_global_load_lds(GLBP(gAl + g), LDSP(base + TOT * 32 + row * 32), 16, 0, 0);
            } else {
                const int br = row - TM;
                const long long g = (long long)(n0 + br) * K + k0 + scol;
                __builtin_amdgcn_global_load_lds(GLBP(gBh + g), LDSP(base + TM * 32 + br * 32), 16, 0, 0);
                if constexpr (SPLIT)
                    __builtin_amdgcn_global_load_lds(GLBP(gBl + g), LDSP(base + TOT * 32 + TM * 32 + br * 32), 16, 0, 0);
            }
        }
    };

    f32x4 acc[4][4];
#pragma unroll
    for (int i = 0; i < 4; ++i)
#pragma unroll
        for (int j = 0; j < 4; ++j)
            acc[i][j] = (f32x4){0.f, 0.f, 0.f, 0.f};

    issue(0, 0);
    const int NIT = K >> 5;
    for (int it = 0; it < NIT; ++it) {
        const int b = it & 1;
        const bool more = (it + 1) < NIT;
        if (more) issue((it + 1) << 5, b ^ 1);
        if constexpr (SPLIT) {
            if (more) asm volatile("s_waitcnt vmcnt(8)" ::: "memory");
            else      asm volatile("s_waitcnt vmcnt(0)" ::: "memory");
        } else {
            if (more) asm volatile("s_waitcnt vmcnt(4)" ::: "memory");
            else      asm volatile("s_waitcnt vmcnt(0)" ::: "memory");
        }
        asm volatile("s_barrier" ::: "memory");

        bf16_t* base = smem + b * BUFSZ;
        bf16_t* sAh = base;
        bf16_t* sBh = base + TM * 32;
        bf16_t* sAl = base + TOT * 32;
        bf16_t* sBl = base + TOT * 32 + TM * 32;

        bf16x8 afh[4], bfh[4], afl[4], bfl[4];
#pragma unroll
        for (int i = 0; i < 4; ++i) {
            const int ao = (wm + i * 16 + l16) * 32 + (quad ^ sw) * 8;
            afh[i] = *(const bf16x8*)(sAh + ao);
            if constexpr (SPLIT) afl[i] = *(const bf16x8*)(sAl + ao);
        }
#pragma unroll
        for (int j = 0; j < 4; ++j) {
            const int bo = (wn + j * 16 + l16) * 32 + (quad ^ sw) * 8;
            bfh[j] = *(const bf16x8*)(sBh + bo);
            if constexpr (SPLIT) bfl[j] = *(const bf16x8*)(sBl + bo);
        }
#pragma unroll
        for (int i = 0; i < 4; ++i)
#pragma unroll
            for (int j = 0; j < 4; ++j) {
                acc[i][j] = __builtin_amdgcn_mfma_f32_16x16x32_bf16(afh[i], bfh[j], acc[i][j], 0, 0, 0);
                if constexpr (SPLIT) {
                    acc[i][j] = __builtin_amdgcn_mfma_f32_16x16x32_bf16(afh[i], bfl[j], acc[i][j], 0, 0, 0);
                    acc[i][j] = __builtin_amdgcn_mfma_f32_16x16x32_bf16(afl[i], bfh[j], acc[i][j], 0, 0, 0);
                }
            }
        asm volatile("s_barrier" ::: "memory");
    }

    const float* bz = (z == 1 && bias2) ? bias2 : bias;
#pragma unroll
    for (int i = 0; i < 4; ++i)
#pragma unroll
        for (int j = 0; j < 4; ++j) {
            const int n = n0 + wn + j * 16 + l16;
            float bvn = 0.f;
            if constexpr (OUT != 0 && !BROW) bvn = bz[n];
#pragma unroll
            for (int r = 0; r < 4; ++r) {
                const int m = m0 + wm + i * 16 + quad * 4 + r;
                const long long idx = z * sC + (long long)m * N + n;
                float v = acc[i][j][r];
                if constexpr (OUT == 0) {
                    Cf[idx] = v * scale;
                } else if constexpr (OUT == 1) {
                    v += bvn;
                    bf16_t h = (bf16_t)v;
                    Ch[idx] = h;
                    Cl[idx] = (bf16_t)(v - (float)h);
                } else {
                    v += BROW ? bz[m] : bvn;
                    Ch[idx] = (bf16_t)v;
                }
            }
        }
}

// ---------------------------------------------------------------------------
// Row softmax + dropout, register-resident (r5, verified): S fp32 -> P bf16.
// ---------------------------------------------------------------------------
__global__ __launch_bounds__(256)
void softmax_dropout(const float* __restrict__ S, bf16_t* __restrict__ P) {
    const unsigned row = blockIdx.x;
    const float* rp = S + (long long)row * LSEQ;
    const int tid = threadIdx.x;

    float v[8];
    *(float4*)(v)     = *(const float4*)(rp + tid * 8);
    *(float4*)(v + 4) = *(const float4*)(rp + tid * 8 + 4);

    float m = v[0];
#pragma unroll
    for (int e = 1; e < 8; ++e) m = fmaxf(m, v[e]);
#pragma unroll
    for (int o = 1; o < 64; o <<= 1) m = fmaxf(m, __shfl_xor(m, o));
    __shared__ float redm[4];
    if ((tid & 63) == 0) redm[tid >> 6] = m;
    __syncthreads();
    m = fmaxf(fmaxf(redm[0], redm[1]), fmaxf(redm[2], redm[3]));

    float s = 0.f;
#pragma unroll
    for (int e = 0; e < 8; ++e) { v[e] = __expf(v[e] - m); s += v[e]; }
#pragma unroll
    for (int o = 1; o < 64; o <<= 1) s += __shfl_xor(s, o);
    __shared__ float reds[4];
    if ((tid & 63) == 0) reds[tid >> 6] = s;
    __syncthreads();
    s = (reds[0] + reds[1]) + (reds[2] + reds[3]);

    const float inv = 2.0f / s;  // dropout /0.5 folded in
    const unsigned nb = row * (unsigned)LSEQ + (unsigned)(tid * 8);
    bf16x8 o8;
#pragma unroll
    for (int e = 0; e < 8; ++e)
        o8[e] = (bf16_t)(dropout_keep(nb + e) ? v[e] * inv : 0.0f);
    *(bf16x8*)(P + (long long)row * LSEQ + tid * 8) = o8;
}

// ---------------------------------------------------------------------------
extern "C" void kernel_launch(void* const* d_in, const int* in_sizes, int n_in,
                              void* d_out, int out_size, void* d_ws, size_t ws_size,
                              hipStream_t stream) {
    const float* query = (const float*)d_in[0];
    const float* key_  = (const float*)d_in[1];
    const float* value = (const float*)d_in[2];
    const float* Wq = (const float*)d_in[3];
    const float* bq = (const float*)d_in[4];
    const float* Wk = (const float*)d_in[5];
    const float* bk = (const float*)d_in[6];
    const float* Wv = (const float*)d_in[7];
    const float* bv = (const float*)d_in[8];
    float* out = (float*)d_out;

    // ws layout (bytes), Q1 = 8192*1024*2 = 16.78MB; total 9*Q1 + 8.4MB = 159.4MB
    char* w = (char*)d_ws;
    const size_t Q1 = (size_t)MROWS * DMODEL * 2;
    bf16_t* Qh  = (bf16_t*)(w);               // [0,2Q1): Qh,Kh  (z-stride NELEM)
    bf16_t* Ql  = (bf16_t*)(w + 2 * Q1);      // [2Q1,4Q1): Ql,Kl
    bf16_t* VT  = (bf16_t*)(w + 4 * Q1);      // [4Q1,5Q1): V^T per batch [D][LK]
    float*  S   = (float*)(w + 5 * Q1);       // [5Q1,9Q1) fp32 scores
    // phase-A aliases inside S region:
    bf16_t* XvH  = (bf16_t*)(w + 5 * Q1);     // V bf16 (hi only)
    bf16_t* XqkH = (bf16_t*)(w + 5 * Q1);     // QK split hi (z-stride NELEM)
    bf16_t* XqkL = (bf16_t*)(w + 7 * Q1);     // QK split lo (z-stride NELEM)
    bf16_t* WTh = (bf16_t*)(w + 9 * Q1);      // 2 z-slots of D*D
    bf16_t* WTl = (bf16_t*)(w + 9 * Q1 + 2 * (size_t)DMODEL * DMODEL * 2);
    bf16_t* P   = Qh;  // [0,2Q1) aliases Qh+Kh (dead after QK^T)

    dim3 b256(256);
    const int NELEM = MROWS * DMODEL;
    const long long DD = (long long)DMODEL * DMODEL;
    dim3 gwt1(DMODEL / 32, DMODEL / 32, 1);
    dim3 gwt2(DMODEL / 32, DMODEL / 32, 2);

    // --- V path: V^T = Wv^T @ Xv^T directly (plain bf16, row-bias)
    // grid: NX=LSEQ/128=16, NY=DMODEL/128=8, NZ=4 -> 512 blocks, SX=2
    split_transpose<<<gwt1, b256, 0, stream>>>(Wv, nullptr, WTh, WTl, DMODEL, DMODEL);
    cvt_bf16<<<dim3(NELEM / 2048), b256, 0, stream>>>(value, XvH, NELEM);
    gemm_mfma<0, 2, 1><<<dim3(512), b256, 0, stream>>>(
        WTh, nullptr, XvH, nullptr, bv, nullptr, nullptr, VT, nullptr,
        DMODEL, LSEQ, DMODEL, 1.f,
        0, (long long)LSEQ * DMODEL, (long long)DMODEL * LSEQ,
        2, DMODEL / 128);

    // --- Q and K projections, fused over z (split precision)
    // grid: NX=8, NY=64, NZ=2 -> 1024 blocks, SX=1
    split_transpose<<<gwt2, b256, 0, stream>>>(Wq, Wk, WTh, WTl, DMODEL, DMODEL);
    split_f32<<<dim3(NELEM / 1024, 2), b256, 0, stream>>>(query, key_, XqkH, XqkL, NELEM);
    gemm_mfma<1, 1, 0><<<dim3(1024), b256, 0, stream>>>(
        XqkH, XqkL, WTh, WTl, bq, bk, nullptr, Qh, Ql,
        MROWS, DMODEL, DMODEL, 1.f,
        (long long)NELEM, DD, (long long)NELEM,
        1, MROWS / 128);

    // --- S = 8 * Q K^T (batched, split precision)
    // grid: NX=16, NY=16, NZ=4 -> 1024 blocks, SX=2
    gemm_mfma<1, 0, 0><<<dim3(1024), b256, 0, stream>>>(
        Qh, Ql, Qh + NELEM, Ql + NELEM, nullptr, nullptr, S, nullptr, nullptr,
        LSEQ, LSEQ, DMODEL, SCORE_SCALE,
        (long long)LSEQ * DMODEL, (long long)LSEQ * DMODEL,
        (long long)LSEQ * LSEQ,
        2, LSEQ / 128);

    // --- softmax + dropout -> P bf16 (aliases Qh/Kh region)
    softmax_dropout<<<dim3(MROWS), b256, 0, stream>>>(S, P);

    // --- O = P V (plain bf16), B operand = V^T [D][LK] per batch
    // grid: NX=8, NY=16, NZ=4 -> 512 blocks, SX=1
    gemm_mfma<0, 0, 0><<<dim3(512), b256, 0, stream>>>(
        P, nullptr, VT, nullptr, nullptr, nullptr, out, nullptr, nullptr,
        LSEQ, DMODEL, LSEQ, 1.f,
        (long long)LSEQ * LSEQ, (long long)DMODEL * LSEQ,
        (long long)LSEQ * DMODEL,
        1, LSEQ / 128);
}